// Round 2
// baseline (288.685 us; speedup 1.0000x reference)
//
#include <hip/hip_runtime.h>
#include <math.h>

#define NN 50000
#define NE 800000
#define CH 64

// Scatter: out[dst, c] += ||edge_attr_e|| * x[src, c]   (out pre-zeroed)
// One 64-lane wave per edge; lane = channel. Coalesced 256B gather per edge,
// contiguous 64-dword atomic cluster per edge.
__global__ __launch_bounds__(256) void scatter_k(
    const float* __restrict__ x,
    const int* __restrict__ ei,
    const float* __restrict__ ea,
    float* __restrict__ s)
{
    const int lane = threadIdx.x & 63;
    int w  = (int)((blockIdx.x * blockDim.x + threadIdx.x) >> 6);
    const int nw = (int)((gridDim.x * blockDim.x) >> 6);
    for (int e = w; e < NE; e += nw) {
        const int src = ei[e];        // edge_index[0, e]
        const int dst = ei[NE + e];   // edge_index[1, e]
        const float a0 = ea[3 * e + 0];
        const float a1 = ea[3 * e + 1];
        const float a2 = ea[3 * e + 2];
        const float nrm = sqrtf(a0 * a0 + a1 * a1 + a2 * a2);
        const float v = nrm * x[(size_t)src * CH + lane];
        atomicAdd(&s[(size_t)dst * CH + lane], v);
    }
}

// Fused epilogue GEMM, in-place on out: out[n,o] = sum_i x[n,i]*psi[o,i] + s[n,i]*phi[o,i]
// where s == out (scatter result). Each block loads its 8 rows of out into LDS
// BEFORE writing, so in-place is safe (rows are block-exclusive).
// Weight LDS layout [o][CH+1]: lane=o reads stride-65 -> bank o%32, 2-way
// aliasing across 64 lanes -> free (m136). xr/sr reads are wave-uniform
// broadcasts.
__global__ __launch_bounds__(256) void out_k(
    const float* __restrict__ x,
    const float* __restrict__ phi,
    const float* __restrict__ psi,
    float* __restrict__ out)
{
    __shared__ float psiW[CH][CH + 1];
    __shared__ float phiW[CH][CH + 1];
    __shared__ float xr[8][CH];
    __shared__ float sr[8][CH];

    for (int t = threadIdx.x; t < CH * CH; t += 256) {
        psiW[t >> 6][t & 63] = psi[t];
        phiW[t >> 6][t & 63] = phi[t];
    }
    const int n0 = blockIdx.x * 8;  // 6250 blocks * 8 == 50000 exactly
    for (int t = threadIdx.x; t < 8 * CH; t += 256) {
        const int nn = t >> 6;
        const int i  = t & 63;
        const size_t idx = (size_t)(n0 + nn) * CH + i;
        xr[nn][i] = x[idx];
        sr[nn][i] = out[idx];
    }
    __syncthreads();

    const int o = threadIdx.x & 63;
    for (int nn = (int)(threadIdx.x >> 6); nn < 8; nn += 4) {
        float acc = 0.f;
#pragma unroll
        for (int i = 0; i < CH; ++i) {
            acc = fmaf(xr[nn][i], psiW[o][i], acc);
            acc = fmaf(sr[nn][i], phiW[o][i], acc);
        }
        out[(size_t)(n0 + nn) * CH + o] = acc;
    }
}

extern "C" void kernel_launch(void* const* d_in, const int* in_sizes, int n_in,
                              void* d_out, int out_size, void* d_ws, size_t ws_size,
                              hipStream_t stream) {
    const float* x   = (const float*)d_in[0];
    const int*   ei  = (const int*)d_in[1];
    const float* ea  = (const float*)d_in[2];
    const float* phi = (const float*)d_in[3];
    const float* psi = (const float*)d_in[4];
    float* out = (float*)d_out;

    // d_out is poisoned 0xAA before every timed launch -> zero it, then use it
    // as the scatter accumulator (no ws_size dependence).
    hipMemsetAsync(out, 0, (size_t)NN * CH * sizeof(float), stream);

    scatter_k<<<4096, 256, 0, stream>>>(x, ei, ea, out);
    out_k<<<NN / 8, 256, 0, stream>>>(x, phi, psi, out);
}